// Round 3
// baseline (2448.410 us; speedup 1.0000x reference)
//
#include <hip/hip_runtime.h>
#include <hip/hip_bf16.h>

// Dims (fixed for this problem)
#define BB 2
#define LL 1024
#define DMODEL 1024
#define DINNER 2048
#define DSTATE 16
#define DCONV 4
#define MM (BB * LL)          // 2048
#define N_XZ (2 * DINNER)     // 4096
#define N_SSM (2 * DSTATE + DINNER) // 2080

// ---------------- tiled GEMM: C[M,N] = A[M,K](f32) @ W[K,N](f32), fp32 acc ----------------
// EPI: 0 = plain f32 store, 1 = +bias then softplus, f32 store
#define BM 64
#define BN 64
#define BK 16
template<int EPI>
__global__ void gemm_kernel(const float* __restrict__ A, int lda,
                            const float* __restrict__ W, int ldw,
                            float* __restrict__ C, int ldc,
                            const float* __restrict__ bias,
                            int M, int N, int K)
{
    __shared__ float As[BK][BM + 1];
    __shared__ float Ws[BK][BN + 1];
    const int tid = threadIdx.x;
    const int row0 = blockIdx.y * BM;
    const int col0 = blockIdx.x * BN;
    const int tx = tid & 15;   // N dir, 16 threads * 4 cols
    const int ty = tid >> 4;   // M dir, 16 threads * 4 rows
    float acc[4][4] = {};

    for (int k0 = 0; k0 < K; k0 += BK) {
        // A tile: BM x BK (stored transposed As[k][m])
        for (int i = tid; i < BM * BK; i += 256) {
            int r = i >> 4, c = i & 15;
            int gr = row0 + r, gc = k0 + c;
            As[c][r] = (gr < M && gc < K) ? A[(size_t)gr * lda + gc] : 0.f;
        }
        // W tile: BK x BN
        for (int i = tid; i < BK * BN; i += 256) {
            int r = i >> 6, c = i & 63;
            int gr = k0 + r, gc = col0 + c;
            Ws[r][c] = (gr < K && gc < N) ? W[(size_t)gr * ldw + gc] : 0.f;
        }
        __syncthreads();
        #pragma unroll
        for (int k = 0; k < BK; ++k) {
            float a[4], w[4];
            #pragma unroll
            for (int i = 0; i < 4; ++i) a[i] = As[k][ty * 4 + i];
            #pragma unroll
            for (int j = 0; j < 4; ++j) w[j] = Ws[k][tx * 4 + j];
            #pragma unroll
            for (int i = 0; i < 4; ++i)
                #pragma unroll
                for (int j = 0; j < 4; ++j)
                    acc[i][j] = fmaf(a[i], w[j], acc[i][j]);
        }
        __syncthreads();
    }

    #pragma unroll
    for (int i = 0; i < 4; ++i) {
        int gr = row0 + ty * 4 + i;
        if (gr >= M) continue;
        #pragma unroll
        for (int j = 0; j < 4; ++j) {
            int gc = col0 + tx * 4 + j;
            if (gc >= N) continue;
            float v = acc[i][j];
            if (EPI == 1) {
                v += bias[gc];
                v = (v > 20.f) ? v : log1pf(__expf(v));
            }
            C[(size_t)gr * ldc + gc] = v;
        }
    }
}

// ---------------- depthwise causal conv (k=4) + bias + SiLU ----------------
__global__ void conv_silu_kernel(const float* __restrict__ xz,
                                 const float* __restrict__ conv_w,
                                 const float* __restrict__ conv_b,
                                 float* __restrict__ u)
{
    int idx = blockIdx.x * blockDim.x + threadIdx.x; // over B*L*DINNER
    if (idx >= BB * LL * DINNER) return;
    int d = idx & (DINNER - 1);
    int l = (idx >> 11) & (LL - 1);
    int b = idx >> 21;
    float acc = conv_b[d];
    #pragma unroll
    for (int j = 0; j < DCONV; ++j) {
        int ll = l - (DCONV - 1) + j;
        if (ll >= 0) {
            float xv = xz[((size_t)(b * LL + ll)) * N_XZ + d];
            acc = fmaf(conv_w[d * DCONV + j], xv, acc);
        }
    }
    float s = acc / (1.f + __expf(-acc));
    u[idx] = s;
}

// ---------------- selective scan ----------------
// one thread per (b,d); h[16] in registers; fused D-skip + z-gating
// y written IN PLACE over u (same index read earlier in the iteration)
__global__ void scan_kernel(const float* __restrict__ dt,   // (B,L,DINNER)
                            float* __restrict__ u,          // (B,L,DINNER), y overwrites
                            const float* __restrict__ ssm,  // (B,L,N_SSM): B=[0:16), C=[16:32)
                            const float* __restrict__ xz,   // z at col DINNER+d
                            const float* __restrict__ A_log,// (DINNER,16)
                            const float* __restrict__ Dp)   // (DINNER)
{
    int d = blockIdx.x * blockDim.x + threadIdx.x;
    int b = blockIdx.y;
    if (d >= DINNER) return;

    float A[DSTATE];
    #pragma unroll
    for (int n = 0; n < DSTATE; ++n) A[n] = -__expf(A_log[d * DSTATE + n]);
    float h[DSTATE];
    #pragma unroll
    for (int n = 0; n < DSTATE; ++n) h[n] = 0.f;
    const float Dd = Dp[d];

    const float* dtb = dt + (size_t)b * LL * DINNER;
    float* ub = u + (size_t)b * LL * DINNER;
    const float* sb = ssm + (size_t)b * LL * N_SSM;
    const float* zb = xz + (size_t)b * LL * N_XZ + DINNER;

    for (int l = 0; l < LL; ++l) {
        float dtv = dtb[(size_t)l * DINNER + d];
        float uv  = ub[(size_t)l * DINNER + d];
        float du  = dtv * uv;
        const float* Bp = sb + (size_t)l * N_SSM;
        const float* Cp = Bp + DSTATE;
        float acc = 0.f;
        #pragma unroll
        for (int n = 0; n < DSTATE; ++n) {
            float dA = __expf(dtv * A[n]);
            h[n] = fmaf(dA, h[n], du * Bp[n]);
            acc = fmaf(h[n], Cp[n], acc);
        }
        acc = fmaf(Dd, uv, acc);
        float zv = zb[(size_t)l * N_XZ + d];
        acc *= zv / (1.f + __expf(-zv));
        ub[(size_t)l * DINNER + d] = acc;  // y over u
    }
}

extern "C" void kernel_launch(void* const* d_in, const int* in_sizes, int n_in,
                              void* d_out, int out_size, void* d_ws, size_t ws_size,
                              hipStream_t stream) {
    const float* x         = (const float*)d_in[0];
    const float* in_proj_w = (const float*)d_in[1];
    const float* conv_w    = (const float*)d_in[2];
    const float* conv_b    = (const float*)d_in[3];
    const float* x_proj_w  = (const float*)d_in[4];
    const float* dt_proj_w = (const float*)d_in[5];
    const float* dt_proj_b = (const float*)d_in[6];
    const float* A_log     = (const float*)d_in[7];
    const float* Dp        = (const float*)d_in[8];
    const float* out_proj_w= (const float*)d_in[9];
    float* out = (float*)d_out;

    // workspace layout (all f32): total = 32 + 16 + 17 + 16 = 81 MB
    float* xz  = (float*)d_ws;                  // MM*N_XZ
    float* u   = xz  + (size_t)MM * N_XZ;       // MM*DINNER (y aliases)
    float* ssm = u   + (size_t)MM * DINNER;     // MM*N_SSM
    float* dt  = ssm + (size_t)MM * N_SSM;      // MM*DINNER

    // 1) xz = x @ in_proj_w   (M x 4096)
    {
        dim3 grid(N_XZ / BN, MM / BM);
        gemm_kernel<0><<<grid, 256, 0, stream>>>(x, DMODEL, in_proj_w, N_XZ,
                                                 xz, N_XZ, nullptr,
                                                 MM, N_XZ, DMODEL);
    }
    // 2) u = silu(depthwise_conv(x_inner) + conv_b)
    {
        int n = BB * LL * DINNER;
        conv_silu_kernel<<<(n + 255) / 256, 256, 0, stream>>>(xz, conv_w, conv_b, u);
    }
    // 3) ssm = u @ x_proj_w    (M x 2080)
    {
        dim3 grid((N_SSM + BN - 1) / BN, MM / BM);
        gemm_kernel<0><<<grid, 256, 0, stream>>>(u, DINNER, x_proj_w, N_SSM,
                                                 ssm, N_SSM, nullptr,
                                                 MM, N_SSM, DINNER);
    }
    // 4) dt = softplus(ssm[:,32:] @ dt_proj_w + dt_proj_b)   (M x 2048)
    {
        dim3 grid(DINNER / BN, MM / BM);
        gemm_kernel<1><<<grid, 256, 0, stream>>>(ssm + 2 * DSTATE, N_SSM, dt_proj_w, DINNER,
                                                 dt, DINNER, dt_proj_b,
                                                 MM, DINNER, DINNER);
    }
    // 5) selective scan -> y (fused D-skip + z gate), y overwrites u
    {
        dim3 grid(DINNER / 256, BB);
        scan_kernel<<<grid, 256, 0, stream>>>(dt, u, ssm, xz, A_log, Dp);
    }
    // 6) out = u(=y) @ out_proj_w  (M x 1024)
    {
        dim3 grid(DMODEL / BN, MM / BM);
        gemm_kernel<0><<<grid, 256, 0, stream>>>(u, DINNER, out_proj_w, DMODEL,
                                                 out, DMODEL, nullptr,
                                                 MM, DMODEL, DINNER);
    }
}

// Round 4
// 1511.015 us; speedup vs baseline: 1.6204x; 1.6204x over previous
//
#include <hip/hip_runtime.h>
#include <hip/hip_bf16.h>

// Dims (fixed for this problem)
#define BB 2
#define LL 1024
#define DMODEL 1024
#define DINNER 2048
#define DSTATE 16
#define DCONV 4
#define MM (BB * LL)          // 2048
#define N_XZ 4096
#define N_SSM 2080
#define N_SSM_PAD 2176        // 17 * 128

typedef __hip_bfloat16 bf16;
typedef short bf16x8 __attribute__((ext_vector_type(8)));   // 8 bf16 = 4 VGPRs
typedef float f32x4 __attribute__((ext_vector_type(4)));

// ---------------- fp32 -> bf16 straight cast ----------------
__global__ void cvt_kernel(const float* __restrict__ in, bf16* __restrict__ out, int n) {
    int i = blockIdx.x * blockDim.x + threadIdx.x;
    if (i < n) out[i] = __float2bfloat16(in[i]);
}

// ---------------- transpose + cast: W fp32 [K,N] -> Wt bf16 [N,K] ----------------
__global__ void transpose_cvt_kernel(const float* __restrict__ in, bf16* __restrict__ out,
                                     int K, int N) {
    __shared__ float tile[32][33];
    const int nb = blockIdx.x * 32, kb = blockIdx.y * 32;
    const int tx = threadIdx.x & 31;
    const int ty = threadIdx.x >> 5;       // 0..7
    #pragma unroll
    for (int i = 0; i < 32; i += 8) {
        int k = kb + ty + i, n = nb + tx;
        tile[ty + i][tx] = (k < K && n < N) ? in[(size_t)k * N + n] : 0.f;
    }
    __syncthreads();
    #pragma unroll
    for (int i = 0; i < 32; i += 8) {
        int n = nb + ty + i, k = kb + tx;
        if (n < N && k < K) out[(size_t)n * K + k] = __float2bfloat16(tile[tx][ty + i]);
    }
}

// ---------------- MFMA GEMM: C[M,N] = A[M,K](bf16) @ Wt[N,K](bf16)^T ----------------
// 128x128 tile, BK=32, 4 waves, each wave 4x4 16x16x32 MFMA tiles.
// EPI: 0 = bf16 store (col<N guard), 1 = +bias softplus fp32 store, 2 = fp32 store
#define TM 128
#define TN 128
#define TK 32
template<int EPI>
__global__ __launch_bounds__(256) void mfma_gemm(
    const bf16* __restrict__ A, int lda,    // [M,K]
    const bf16* __restrict__ Wt, int ldw,   // [Npad,K] (row n = W[:,n])
    float* __restrict__ Cf, bf16* __restrict__ Cb, int ldc,
    const float* __restrict__ bias,
    int N, int K)
{
    __shared__ __align__(16) bf16 As[TM][TK + 8];   // +8 bf16 pad: uniform bank groups
    __shared__ __align__(16) bf16 Bs[TN][TK + 8];
    const int tid = threadIdx.x;
    const int wave = tid >> 6, lane = tid & 63;
    const int wm = (wave >> 1) * 64, wn = (wave & 1) * 64;
    const int m0 = blockIdx.y * TM, n0 = blockIdx.x * TN;
    const int lm = lane & 15;      // fragment row (A) / col (B) / col (D)
    const int kq = lane >> 4;      // k-quad (frag) / row-quad (D)

    f32x4 acc[4][4] = {};          // [mi][ni]

    const int sr = tid >> 2;       // staging row within 64-row round
    const int sc = tid & 3;        // 16B chunk (8 bf16)

    for (int k0 = 0; k0 < K; k0 += TK) {
        #pragma unroll
        for (int rd = 0; rd < 2; ++rd) {
            int row = rd * 64 + sr;
            uint4 v = *(const uint4*)(A + (size_t)(m0 + row) * lda + k0 + sc * 8);
            *(uint4*)(&As[row][sc * 8]) = v;
        }
        #pragma unroll
        for (int rd = 0; rd < 2; ++rd) {
            int row = rd * 64 + sr;
            uint4 v = *(const uint4*)(Wt + (size_t)(n0 + row) * ldw + k0 + sc * 8);
            *(uint4*)(&Bs[row][sc * 8]) = v;
        }
        __syncthreads();
        bf16x8 af[4], bfr[4];
        #pragma unroll
        for (int i = 0; i < 4; ++i)
            af[i] = *(const bf16x8*)(&As[wm + i * 16 + lm][kq * 8]);
        #pragma unroll
        for (int j = 0; j < 4; ++j)
            bfr[j] = *(const bf16x8*)(&Bs[wn + j * 16 + lm][kq * 8]);
        #pragma unroll
        for (int i = 0; i < 4; ++i)
            #pragma unroll
            for (int j = 0; j < 4; ++j)
                acc[i][j] = __builtin_amdgcn_mfma_f32_16x16x32_bf16(af[i], bfr[j], acc[i][j], 0, 0, 0);
        __syncthreads();
    }

    // epilogue: D layout col=lane&15, row=(lane>>4)*4+r  (m89-verified)
    #pragma unroll
    for (int i = 0; i < 4; ++i) {
        #pragma unroll
        for (int j = 0; j < 4; ++j) {
            int gcol = n0 + wn + j * 16 + lm;
            if (EPI == 0 && gcol >= N) continue;
            #pragma unroll
            for (int r = 0; r < 4; ++r) {
                int grow = m0 + wm + i * 16 + kq * 4 + r;
                float v = acc[i][j][r];
                if (EPI == 1) {
                    v += bias[gcol];
                    v = (v > 20.f) ? v : log1pf(__expf(v));
                    Cf[(size_t)grow * ldc + gcol] = v;
                } else if (EPI == 2) {
                    Cf[(size_t)grow * ldc + gcol] = v;
                } else {
                    Cb[(size_t)grow * ldc + gcol] = __float2bfloat16(v);
                }
            }
        }
    }
}

// ---------------- depthwise causal conv (k=4) + bias + SiLU (bf16 io) ----------------
__global__ void conv_silu_kernel(const bf16* __restrict__ xz,
                                 const float* __restrict__ conv_w,
                                 const float* __restrict__ conv_b,
                                 bf16* __restrict__ u)
{
    int idx = blockIdx.x * blockDim.x + threadIdx.x;
    if (idx >= BB * LL * DINNER) return;
    int d = idx & (DINNER - 1);
    int l = (idx >> 11) & (LL - 1);
    int b = idx >> 21;
    float acc = conv_b[d];
    #pragma unroll
    for (int j = 0; j < DCONV; ++j) {
        int ll = l - (DCONV - 1) + j;
        if (ll >= 0) {
            float xv = (float)xz[((size_t)(b * LL + ll)) * N_XZ + d];
            acc = fmaf(conv_w[d * DCONV + j], xv, acc);
        }
    }
    u[idx] = __float2bfloat16(acc / (1.f + __expf(-acc)));
}

// ---------------- selective scan (bf16 io, fp32 state), y over u in place ----------------
__global__ void scan_kernel(const float* __restrict__ dt,   // (B,L,DINNER) f32
                            bf16* __restrict__ u,           // (B,L,DINNER) bf16; y overwrites
                            const bf16* __restrict__ ssm,   // (B,L,N_SSM)
                            const bf16* __restrict__ xz,    // z at col DINNER+d
                            const float* __restrict__ A_log,
                            const float* __restrict__ Dp)
{
    int d = blockIdx.x * blockDim.x + threadIdx.x;
    int b = blockIdx.y;
    if (d >= DINNER) return;

    float A[DSTATE];
    #pragma unroll
    for (int n = 0; n < DSTATE; ++n) A[n] = -__expf(A_log[d * DSTATE + n]);
    float h[DSTATE];
    #pragma unroll
    for (int n = 0; n < DSTATE; ++n) h[n] = 0.f;
    const float Dd = Dp[d];

    const float* dtb = dt + (size_t)b * LL * DINNER;
    bf16* ub = u + (size_t)b * LL * DINNER;
    const bf16* sb = ssm + (size_t)b * LL * N_SSM;
    const bf16* zb = xz + (size_t)b * LL * N_XZ + DINNER;

    for (int l = 0; l < LL; ++l) {
        float dtv = dtb[(size_t)l * DINNER + d];
        float uv  = (float)ub[(size_t)l * DINNER + d];
        float du  = dtv * uv;
        const bf16* Bp = sb + (size_t)l * N_SSM;
        const bf16* Cp = Bp + DSTATE;
        float acc = 0.f;
        #pragma unroll
        for (int n = 0; n < DSTATE; ++n) {
            float dA = __expf(dtv * A[n]);
            h[n] = fmaf(dA, h[n], du * (float)Bp[n]);
            acc = fmaf(h[n], (float)Cp[n], acc);
        }
        acc = fmaf(Dd, uv, acc);
        float zv = (float)zb[(size_t)l * N_XZ + d];
        acc *= zv / (1.f + __expf(-zv));
        ub[(size_t)l * DINNER + d] = __float2bfloat16(acc);
    }
}

extern "C" void kernel_launch(void* const* d_in, const int* in_sizes, int n_in,
                              void* d_out, int out_size, void* d_ws, size_t ws_size,
                              hipStream_t stream) {
    const float* x         = (const float*)d_in[0];
    const float* in_proj_w = (const float*)d_in[1];
    const float* conv_w    = (const float*)d_in[2];
    const float* conv_b    = (const float*)d_in[3];
    const float* x_proj_w  = (const float*)d_in[4];
    const float* dt_proj_w = (const float*)d_in[5];
    const float* dt_proj_b = (const float*)d_in[6];
    const float* A_log     = (const float*)d_in[7];
    const float* Dp        = (const float*)d_in[8];
    const float* out_proj_w= (const float*)d_in[9];
    float* out = (float*)d_out;

    // workspace layout (~80.4 MB); xbf aliases dt region (xbf dead before dt written)
    char* p = (char*)d_ws;
    float* dt   = (float*)p;                          p += (size_t)MM * DINNER * 4;  // 16.78 MB
    bf16*  xbf  = (bf16*)dt;                          // 4.19 MB, aliases dt
    bf16*  xz   = (bf16*)p;                           p += (size_t)MM * N_XZ * 2;    // 16.78
    bf16*  u    = (bf16*)p;                           p += (size_t)MM * DINNER * 2;  // 8.39 (y aliases)
    bf16*  ssm  = (bf16*)p;                           p += (size_t)MM * N_SSM * 2;   // 8.52
    bf16*  Wt1  = (bf16*)p;                           p += (size_t)N_XZ * DMODEL * 2;     // 8.39
    bf16*  Wt2  = (bf16*)p;                           p += (size_t)N_SSM_PAD * DINNER * 2;// 8.91
    bf16*  Wt3  = (bf16*)p;                           p += (size_t)DINNER * DINNER * 2;   // 8.39
    bf16*  Wt4  = (bf16*)p;                           p += (size_t)DMODEL * DINNER * 2;   // 4.19

    // 0) converts / transposes
    {
        int n = MM * DMODEL;
        cvt_kernel<<<(n + 255) / 256, 256, 0, stream>>>(x, xbf, n);
        transpose_cvt_kernel<<<dim3(N_XZ / 32, DMODEL / 32), 256, 0, stream>>>(in_proj_w, Wt1, DMODEL, N_XZ);
        transpose_cvt_kernel<<<dim3((N_SSM + 31) / 32, DINNER / 32), 256, 0, stream>>>(x_proj_w, Wt2, DINNER, N_SSM);
        transpose_cvt_kernel<<<dim3(DINNER / 32, DINNER / 32), 256, 0, stream>>>(dt_proj_w, Wt3, DINNER, DINNER);
        transpose_cvt_kernel<<<dim3(DMODEL / 32, DINNER / 32), 256, 0, stream>>>(out_proj_w, Wt4, DINNER, DMODEL);
    }
    // 1) xz = xbf @ W1   (2048 x 4096, K=1024), bf16
    mfma_gemm<0><<<dim3(N_XZ / TN, MM / TM), 256, 0, stream>>>(
        xbf, DMODEL, Wt1, DMODEL, nullptr, xz, N_XZ, nullptr, N_XZ, DMODEL);
    // 2) u = silu(conv(x_inner)+b)
    {
        int n = BB * LL * DINNER;
        conv_silu_kernel<<<(n + 255) / 256, 256, 0, stream>>>(xz, conv_w, conv_b, u);
    }
    // 3) ssm = u @ W2    (2048 x 2080, K=2048), bf16, col-guarded
    mfma_gemm<0><<<dim3(N_SSM_PAD / TN, MM / TM), 256, 0, stream>>>(
        u, DINNER, Wt2, DINNER, nullptr, ssm, N_SSM, nullptr, N_SSM, DINNER);
    // 4) dt = softplus(ssm[:,32:] @ W3 + b)  (2048 x 2048, K=2048), fp32
    mfma_gemm<1><<<dim3(DINNER / TN, MM / TM), 256, 0, stream>>>(
        ssm + 2 * DSTATE, N_SSM, Wt3, DINNER, dt, nullptr, DINNER, dt_proj_b, DINNER, DINNER);
    // 5) selective scan (y over u)
    scan_kernel<<<dim3(DINNER / 256, BB), 256, 0, stream>>>(dt, u, ssm, xz, A_log, Dp);
    // 6) out = y @ W4    (2048 x 1024, K=2048), fp32
    mfma_gemm<2><<<dim3(DMODEL / TN, MM / TM), 256, 0, stream>>>(
        u, DINNER, Wt4, DINNER, out, nullptr, DMODEL, nullptr, DMODEL, DINNER);
}

// Round 5
// 1046.309 us; speedup vs baseline: 2.3400x; 1.4441x over previous
//
#include <hip/hip_runtime.h>
#include <hip/hip_bf16.h>

// Dims (fixed for this problem)
#define BB 2
#define LL 1024
#define DMODEL 1024
#define DINNER 2048
#define DSTATE 16
#define DCONV 4
#define MM (BB * LL)          // 2048
#define N_XZ 4096
#define N_SSM 2080
#define N_SSM_PAD 2176        // 17 * 128

typedef __hip_bfloat16 bf16;
typedef short bf16x8 __attribute__((ext_vector_type(8)));   // 8 bf16 = 4 VGPRs
typedef float f32x4 __attribute__((ext_vector_type(4)));

// ---------------- fp32 -> bf16 straight cast ----------------
__global__ void cvt_kernel(const float* __restrict__ in, bf16* __restrict__ out, int n) {
    int i = blockIdx.x * blockDim.x + threadIdx.x;
    if (i < n) out[i] = __float2bfloat16(in[i]);
}

// ---------------- transpose + cast: W fp32 [K,N] -> Wt bf16 [N,K] ----------------
__global__ void transpose_cvt_kernel(const float* __restrict__ in, bf16* __restrict__ out,
                                     int K, int N) {
    __shared__ float tile[32][33];
    const int nb = blockIdx.x * 32, kb = blockIdx.y * 32;
    const int tx = threadIdx.x & 31;
    const int ty = threadIdx.x >> 5;       // 0..7
    #pragma unroll
    for (int i = 0; i < 32; i += 8) {
        int k = kb + ty + i, n = nb + tx;
        tile[ty + i][tx] = (k < K && n < N) ? in[(size_t)k * N + n] : 0.f;
    }
    __syncthreads();
    #pragma unroll
    for (int i = 0; i < 32; i += 8) {
        int n = nb + ty + i, k = kb + tx;
        if (n < N && k < K) out[(size_t)n * K + k] = __float2bfloat16(tile[tx][ty + i]);
    }
}

// ---------------- MFMA GEMM: C[M,N] = A[M,K](bf16) @ Wt[N,K](bf16)^T ----------------
#define TM 128
#define TN 128
#define TK 32
template<int EPI>
__global__ __launch_bounds__(256) void mfma_gemm(
    const bf16* __restrict__ A, int lda,    // [M,K]
    const bf16* __restrict__ Wt, int ldw,   // [Npad,K]
    float* __restrict__ Cf, bf16* __restrict__ Cb, int ldc,
    const float* __restrict__ bias,
    int N, int K)
{
    __shared__ __align__(16) bf16 As[TM][TK + 8];
    __shared__ __align__(16) bf16 Bs[TN][TK + 8];
    const int tid = threadIdx.x;
    const int wave = tid >> 6, lane = tid & 63;
    const int wm = (wave >> 1) * 64, wn = (wave & 1) * 64;
    const int m0 = blockIdx.y * TM, n0 = blockIdx.x * TN;
    const int lm = lane & 15;
    const int kq = lane >> 4;

    f32x4 acc[4][4] = {};

    const int sr = tid >> 2;
    const int sc = tid & 3;

    for (int k0 = 0; k0 < K; k0 += TK) {
        #pragma unroll
        for (int rd = 0; rd < 2; ++rd) {
            int row = rd * 64 + sr;
            uint4 v = *(const uint4*)(A + (size_t)(m0 + row) * lda + k0 + sc * 8);
            *(uint4*)(&As[row][sc * 8]) = v;
        }
        #pragma unroll
        for (int rd = 0; rd < 2; ++rd) {
            int row = rd * 64 + sr;
            uint4 v = *(const uint4*)(Wt + (size_t)(n0 + row) * ldw + k0 + sc * 8);
            *(uint4*)(&Bs[row][sc * 8]) = v;
        }
        __syncthreads();
        bf16x8 af[4], bfr[4];
        #pragma unroll
        for (int i = 0; i < 4; ++i)
            af[i] = *(const bf16x8*)(&As[wm + i * 16 + lm][kq * 8]);
        #pragma unroll
        for (int j = 0; j < 4; ++j)
            bfr[j] = *(const bf16x8*)(&Bs[wn + j * 16 + lm][kq * 8]);
        #pragma unroll
        for (int i = 0; i < 4; ++i)
            #pragma unroll
            for (int j = 0; j < 4; ++j)
                acc[i][j] = __builtin_amdgcn_mfma_f32_16x16x32_bf16(af[i], bfr[j], acc[i][j], 0, 0, 0);
        __syncthreads();
    }

    #pragma unroll
    for (int i = 0; i < 4; ++i) {
        #pragma unroll
        for (int j = 0; j < 4; ++j) {
            int gcol = n0 + wn + j * 16 + lm;
            if (EPI == 0 && gcol >= N) continue;
            #pragma unroll
            for (int r = 0; r < 4; ++r) {
                int grow = m0 + wm + i * 16 + kq * 4 + r;
                float v = acc[i][j][r];
                if (EPI == 1) {
                    v += bias[gcol];
                    v = (v > 20.f) ? v : log1pf(__expf(v));
                    Cf[(size_t)grow * ldc + gcol] = v;
                } else if (EPI == 2) {
                    Cf[(size_t)grow * ldc + gcol] = v;
                } else {
                    Cb[(size_t)grow * ldc + gcol] = __float2bfloat16(v);
                }
            }
        }
    }
}

// ---------------- depthwise causal conv (k=4) + bias + SiLU (bf16 io) ----------------
__global__ void conv_silu_kernel(const bf16* __restrict__ xz,
                                 const float* __restrict__ conv_w,
                                 const float* __restrict__ conv_b,
                                 bf16* __restrict__ u)
{
    int idx = blockIdx.x * blockDim.x + threadIdx.x;
    if (idx >= BB * LL * DINNER) return;
    int d = idx & (DINNER - 1);
    int l = (idx >> 11) & (LL - 1);
    int b = idx >> 21;
    float acc = conv_b[d];
    #pragma unroll
    for (int j = 0; j < DCONV; ++j) {
        int ll = l - (DCONV - 1) + j;
        if (ll >= 0) {
            float xv = (float)xz[((size_t)(b * LL + ll)) * N_XZ + d];
            acc = fmaf(conv_w[d * DCONV + j], xv, acc);
        }
    }
    u[idx] = __float2bfloat16(acc / (1.f + __expf(-acc)));
}

// ---------------- DPP 16-lane rotate-reduce (sum broadcast to all 16 lanes) -------------
__device__ __forceinline__ float row16_sum(float x) {
    // row_ror:n = 0x120 | n ; rotations stay within the 16-lane DPP row
    int xi;
    xi = __builtin_amdgcn_update_dpp(0, __float_as_int(x), 0x128, 0xF, 0xF, true);
    x += __int_as_float(xi);
    xi = __builtin_amdgcn_update_dpp(0, __float_as_int(x), 0x124, 0xF, 0xF, true);
    x += __int_as_float(xi);
    xi = __builtin_amdgcn_update_dpp(0, __float_as_int(x), 0x122, 0xF, 0xF, true);
    x += __int_as_float(xi);
    xi = __builtin_amdgcn_update_dpp(0, __float_as_int(x), 0x121, 0xF, 0xF, true);
    x += __int_as_float(xi);
    return x;
}

// ---------------- selective scan v2: one lane per (b,d,n) ----------------
// 256 threads = 16 d-channels per block; grid (DINNER/16, BB) = 256 blocks.
// y (gated, +D-skip) overwritten onto u in place.
__global__ __launch_bounds__(256) void scan_kernel(
    const float* __restrict__ dt,   // (B,L,DINNER) f32
    bf16* __restrict__ u,           // (B,L,DINNER) bf16; y overwrites
    const bf16* __restrict__ ssm,   // (B,L,N_SSM): B=[0:16), C=[16:32)
    const bf16* __restrict__ xz,    // z at col DINNER+d
    const float* __restrict__ A_log,
    const float* __restrict__ Dp)
{
    const int tid = threadIdx.x;
    const int n = tid & 15;          // state index (DPP row position)
    const int dloc = tid >> 4;       // 0..15
    const int d = blockIdx.x * 16 + dloc;
    const int b = blockIdx.y;

    const float A = -__expf(A_log[d * DSTATE + n]);
    const float Dd = Dp[d];
    float h = 0.f;

    const float* dtp = dt + (size_t)b * LL * DINNER + d;
    bf16* up = u + (size_t)b * LL * DINNER + d;
    const bf16* sp = ssm + (size_t)b * LL * N_SSM + n;
    const bf16* zp = xz + (size_t)b * LL * N_XZ + DINNER + d;

    #pragma unroll 2
    for (int l = 0; l < LL; ++l) {
        float dtv = *dtp;
        float uv  = (float)*up;
        float Bv  = (float)sp[0];
        float Cv  = (float)sp[DSTATE];
        float a   = __expf(dtv * A);
        h = fmaf(a, h, dtv * uv * Bv);
        float p = row16_sum(h * Cv);
        float zv = (float)*zp;
        float acc = fmaf(Dd, uv, p);
        acc *= zv / (1.f + __expf(-zv));
        if (n == 0) *up = __float2bfloat16(acc);
        dtp += DINNER; up += DINNER; sp += N_SSM; zp += N_XZ;
    }
}

extern "C" void kernel_launch(void* const* d_in, const int* in_sizes, int n_in,
                              void* d_out, int out_size, void* d_ws, size_t ws_size,
                              hipStream_t stream) {
    const float* x         = (const float*)d_in[0];
    const float* in_proj_w = (const float*)d_in[1];
    const float* conv_w    = (const float*)d_in[2];
    const float* conv_b    = (const float*)d_in[3];
    const float* x_proj_w  = (const float*)d_in[4];
    const float* dt_proj_w = (const float*)d_in[5];
    const float* dt_proj_b = (const float*)d_in[6];
    const float* A_log     = (const float*)d_in[7];
    const float* Dp        = (const float*)d_in[8];
    const float* out_proj_w= (const float*)d_in[9];
    float* out = (float*)d_out;

    // workspace layout (~80.4 MB); xbf aliases dt region (xbf dead before dt written)
    char* p = (char*)d_ws;
    float* dt   = (float*)p;                          p += (size_t)MM * DINNER * 4;
    bf16*  xbf  = (bf16*)dt;
    bf16*  xz   = (bf16*)p;                           p += (size_t)MM * N_XZ * 2;
    bf16*  u    = (bf16*)p;                           p += (size_t)MM * DINNER * 2;
    bf16*  ssm  = (bf16*)p;                           p += (size_t)MM * N_SSM * 2;
    bf16*  Wt1  = (bf16*)p;                           p += (size_t)N_XZ * DMODEL * 2;
    bf16*  Wt2  = (bf16*)p;                           p += (size_t)N_SSM_PAD * DINNER * 2;
    bf16*  Wt3  = (bf16*)p;                           p += (size_t)DINNER * DINNER * 2;
    bf16*  Wt4  = (bf16*)p;                           p += (size_t)DMODEL * DINNER * 2;

    // 0) converts / transposes
    {
        int n = MM * DMODEL;
        cvt_kernel<<<(n + 255) / 256, 256, 0, stream>>>(x, xbf, n);
        transpose_cvt_kernel<<<dim3(N_XZ / 32, DMODEL / 32), 256, 0, stream>>>(in_proj_w, Wt1, DMODEL, N_XZ);
        transpose_cvt_kernel<<<dim3((N_SSM + 31) / 32, DINNER / 32), 256, 0, stream>>>(x_proj_w, Wt2, DINNER, N_SSM);
        transpose_cvt_kernel<<<dim3(DINNER / 32, DINNER / 32), 256, 0, stream>>>(dt_proj_w, Wt3, DINNER, DINNER);
        transpose_cvt_kernel<<<dim3(DMODEL / 32, DINNER / 32), 256, 0, stream>>>(out_proj_w, Wt4, DINNER, DMODEL);
    }
    // 1) xz = xbf @ W1   (2048 x 4096, K=1024), bf16
    mfma_gemm<0><<<dim3(N_XZ / TN, MM / TM), 256, 0, stream>>>(
        xbf, DMODEL, Wt1, DMODEL, nullptr, xz, N_XZ, nullptr, N_XZ, DMODEL);
    // 2) u = silu(conv(x_inner)+b)
    {
        int n = BB * LL * DINNER;
        conv_silu_kernel<<<(n + 255) / 256, 256, 0, stream>>>(xz, conv_w, conv_b, u);
    }
    // 3) ssm = u @ W2    (2048 x 2080, K=2048), bf16, col-guarded
    mfma_gemm<0><<<dim3(N_SSM_PAD / TN, MM / TM), 256, 0, stream>>>(
        u, DINNER, Wt2, DINNER, nullptr, ssm, N_SSM, nullptr, N_SSM, DINNER);
    // 4) dt = softplus(ssm[:,32:] @ W3 + b)  (2048 x 2048, K=2048), fp32
    mfma_gemm<1><<<dim3(DINNER / TN, MM / TM), 256, 0, stream>>>(
        ssm + 2 * DSTATE, N_SSM, Wt3, DINNER, dt, nullptr, DINNER, dt_proj_b, DINNER, DINNER);
    // 5) selective scan v2 (y over u): lane per (b,d,n), DPP reduce
    scan_kernel<<<dim3(DINNER / 16, BB), 256, 0, stream>>>(dt, u, ssm, xz, A_log, Dp);
    // 6) out = y @ W4    (2048 x 1024, K=2048), fp32
    mfma_gemm<2><<<dim3(DMODEL / TN, MM / TM), 256, 0, stream>>>(
        u, DINNER, Wt4, DINNER, out, nullptr, DMODEL, nullptr, DMODEL, DINNER);
}

// Round 6
// 496.593 us; speedup vs baseline: 4.9304x; 2.1070x over previous
//
#include <hip/hip_runtime.h>
#include <hip/hip_bf16.h>

// Dims (fixed for this problem)
#define BB 2
#define LL 1024
#define DMODEL 1024
#define DINNER 2048
#define DSTATE 16
#define DCONV 4
#define MM (BB * LL)          // 2048
#define N_XZ 4096
#define N_SSM 2080
#define N_SSM_PAD 2176        // 17 * 128
#define CCH 32                // chunks over L
#define LCH 32                // chunk length (CCH*LCH == LL)

typedef __hip_bfloat16 bf16;
typedef short bf16x8 __attribute__((ext_vector_type(8)));
typedef float f32x4 __attribute__((ext_vector_type(4)));

// ---------------- fp32 -> bf16 straight cast ----------------
__global__ void cvt_kernel(const float* __restrict__ in, bf16* __restrict__ out, int n) {
    int i = blockIdx.x * blockDim.x + threadIdx.x;
    if (i < n) out[i] = __float2bfloat16(in[i]);
}

// ---------------- transpose + cast: W fp32 [K,N] -> Wt bf16 [N,K] ----------------
__global__ void transpose_cvt_kernel(const float* __restrict__ in, bf16* __restrict__ out,
                                     int K, int N) {
    __shared__ float tile[32][33];
    const int nb = blockIdx.x * 32, kb = blockIdx.y * 32;
    const int tx = threadIdx.x & 31;
    const int ty = threadIdx.x >> 5;
    #pragma unroll
    for (int i = 0; i < 32; i += 8) {
        int k = kb + ty + i, n = nb + tx;
        tile[ty + i][tx] = (k < K && n < N) ? in[(size_t)k * N + n] : 0.f;
    }
    __syncthreads();
    #pragma unroll
    for (int i = 0; i < 32; i += 8) {
        int n = nb + ty + i, k = kb + tx;
        if (n < N && k < K) out[(size_t)n * K + k] = __float2bfloat16(tile[tx][ty + i]);
    }
}

// ---------------- MFMA GEMM: C[M,N] = A[M,K](bf16) @ Wt[N,K](bf16)^T ----------------
#define TM 128
#define TN 128
#define TK 32
template<int EPI>
__global__ __launch_bounds__(256) void mfma_gemm(
    const bf16* __restrict__ A, int lda,
    const bf16* __restrict__ Wt, int ldw,
    float* __restrict__ Cf, bf16* __restrict__ Cb, int ldc,
    const float* __restrict__ bias,
    int N, int K)
{
    __shared__ __align__(16) bf16 As[TM][TK + 8];
    __shared__ __align__(16) bf16 Bs[TN][TK + 8];
    const int tid = threadIdx.x;
    const int wave = tid >> 6, lane = tid & 63;
    const int wm = (wave >> 1) * 64, wn = (wave & 1) * 64;
    const int m0 = blockIdx.y * TM, n0 = blockIdx.x * TN;
    const int lm = lane & 15;
    const int kq = lane >> 4;

    f32x4 acc[4][4] = {};

    const int sr = tid >> 2;
    const int sc = tid & 3;

    for (int k0 = 0; k0 < K; k0 += TK) {
        #pragma unroll
        for (int rd = 0; rd < 2; ++rd) {
            int row = rd * 64 + sr;
            uint4 v = *(const uint4*)(A + (size_t)(m0 + row) * lda + k0 + sc * 8);
            *(uint4*)(&As[row][sc * 8]) = v;
        }
        #pragma unroll
        for (int rd = 0; rd < 2; ++rd) {
            int row = rd * 64 + sr;
            uint4 v = *(const uint4*)(Wt + (size_t)(n0 + row) * ldw + k0 + sc * 8);
            *(uint4*)(&Bs[row][sc * 8]) = v;
        }
        __syncthreads();
        bf16x8 af[4], bfr[4];
        #pragma unroll
        for (int i = 0; i < 4; ++i)
            af[i] = *(const bf16x8*)(&As[wm + i * 16 + lm][kq * 8]);
        #pragma unroll
        for (int j = 0; j < 4; ++j)
            bfr[j] = *(const bf16x8*)(&Bs[wn + j * 16 + lm][kq * 8]);
        #pragma unroll
        for (int i = 0; i < 4; ++i)
            #pragma unroll
            for (int j = 0; j < 4; ++j)
                acc[i][j] = __builtin_amdgcn_mfma_f32_16x16x32_bf16(af[i], bfr[j], acc[i][j], 0, 0, 0);
        __syncthreads();
    }

    #pragma unroll
    for (int i = 0; i < 4; ++i) {
        #pragma unroll
        for (int j = 0; j < 4; ++j) {
            int gcol = n0 + wn + j * 16 + lm;
            if (EPI == 0 && gcol >= N) continue;
            #pragma unroll
            for (int r = 0; r < 4; ++r) {
                int grow = m0 + wm + i * 16 + kq * 4 + r;
                float v = acc[i][j][r];
                if (EPI == 1) {
                    v += bias[gcol];
                    v = (v > 20.f) ? v : log1pf(__expf(v));
                    Cf[(size_t)grow * ldc + gcol] = v;
                } else if (EPI == 2) {
                    Cf[(size_t)grow * ldc + gcol] = v;
                } else {
                    Cb[(size_t)grow * ldc + gcol] = __float2bfloat16(v);
                }
            }
        }
    }
}

// ---------------- depthwise causal conv (k=4) + bias + SiLU (bf16 io) ----------------
__global__ void conv_silu_kernel(const bf16* __restrict__ xz,
                                 const float* __restrict__ conv_w,
                                 const float* __restrict__ conv_b,
                                 bf16* __restrict__ u)
{
    int idx = blockIdx.x * blockDim.x + threadIdx.x;
    if (idx >= BB * LL * DINNER) return;
    int d = idx & (DINNER - 1);
    int l = (idx >> 11) & (LL - 1);
    int b = idx >> 21;
    float acc = conv_b[d];
    #pragma unroll
    for (int j = 0; j < DCONV; ++j) {
        int ll = l - (DCONV - 1) + j;
        if (ll >= 0) {
            float xv = (float)xz[((size_t)(b * LL + ll)) * N_XZ + d];
            acc = fmaf(conv_w[d * DCONV + j], xv, acc);
        }
    }
    u[idx] = __float2bfloat16(acc / (1.f + __expf(-acc)));
}

// ---------------- DPP 16-lane rotate-reduce (sum broadcast to all 16 lanes) -------------
__device__ __forceinline__ float row16_sum(float x) {
    int xi;
    xi = __builtin_amdgcn_update_dpp(0, __float_as_int(x), 0x128, 0xF, 0xF, true);
    x += __int_as_float(xi);
    xi = __builtin_amdgcn_update_dpp(0, __float_as_int(x), 0x124, 0xF, 0xF, true);
    x += __int_as_float(xi);
    xi = __builtin_amdgcn_update_dpp(0, __float_as_int(x), 0x122, 0xF, 0xF, true);
    x += __int_as_float(xi);
    xi = __builtin_amdgcn_update_dpp(0, __float_as_int(x), 0x121, 0xF, 0xF, true);
    x += __int_as_float(xi);
    return x;
}

// ---------------- scan phase A: per-chunk local scan -> (P, h_end) ----------------
// grid (DINNER/16, CCH, BB), block 256; lane per (d,n)
__global__ __launch_bounds__(256) void scan_phase_a(
    const float* __restrict__ dt, const bf16* __restrict__ u,
    const bf16* __restrict__ ssm, const float* __restrict__ A_log,
    float* __restrict__ chunkP, float* __restrict__ chunkH)
{
    const int tid = threadIdx.x;
    const int n = tid & 15, dloc = tid >> 4;
    const int d = blockIdx.x * 16 + dloc;
    const int c = blockIdx.y, b = blockIdx.z;
    const int l0 = c * LCH;

    const float A = -__expf(A_log[d * DSTATE + n]);
    float h = 0.f, sdt = 0.f;
    const float* dtp = dt + ((size_t)b * LL + l0) * DINNER + d;
    const bf16* up = u + ((size_t)b * LL + l0) * DINNER + d;
    const bf16* sp = ssm + ((size_t)b * LL + l0) * N_SSM + n;
    #pragma unroll 4
    for (int i = 0; i < LCH; ++i) {
        float dtv = *dtp;
        float uv  = (float)*up;
        float Bv  = (float)*sp;
        float a   = __expf(dtv * A);
        h = fmaf(a, h, dtv * uv * Bv);
        sdt += dtv;
        dtp += DINNER; up += DINNER; sp += N_SSM;
    }
    size_t idx = (((size_t)b * CCH + c) * DINNER + d) * DSTATE + n;
    chunkP[idx] = __expf(A * sdt);
    chunkH[idx] = h;
}

// ---------------- scan phase P: exclusive prefix over chunks, in place on chunkH ----
__global__ __launch_bounds__(256) void scan_phase_p(
    const float* __restrict__ chunkP, float* __restrict__ chunkH)
{
    int gid = blockIdx.x * 256 + threadIdx.x;   // over B*DINNER*DSTATE = 65536
    int n = gid & 15;
    int d = (gid >> 4) & (DINNER - 1);
    int b = gid >> 15;
    const size_t stride = (size_t)DINNER * DSTATE;
    size_t idx = ((size_t)b * CCH * DINNER + d) * DSTATE + n;
    float H = 0.f;
    for (int c = 0; c < CCH; ++c) {
        float P  = chunkP[idx];
        float hl = chunkH[idx];
        chunkH[idx] = H;           // exclusive prefix
        H = fmaf(P, H, hl);
        idx += stride;
    }
}

// ---------------- scan phase B: apply with corrected h0, emit gated y over u --------
__global__ __launch_bounds__(256) void scan_phase_b(
    const float* __restrict__ dt, bf16* __restrict__ u,
    const bf16* __restrict__ ssm, const bf16* __restrict__ xz,
    const float* __restrict__ A_log, const float* __restrict__ Dp,
    const float* __restrict__ chunkH)
{
    const int tid = threadIdx.x;
    const int n = tid & 15, dloc = tid >> 4;
    const int d = blockIdx.x * 16 + dloc;
    const int c = blockIdx.y, b = blockIdx.z;
    const int l0 = c * LCH;

    const float A = -__expf(A_log[d * DSTATE + n]);
    const float Dd = Dp[d];
    float h = chunkH[(((size_t)b * CCH + c) * DINNER + d) * DSTATE + n];

    const float* dtp = dt + ((size_t)b * LL + l0) * DINNER + d;
    bf16* up = u + ((size_t)b * LL + l0) * DINNER + d;
    const bf16* sp = ssm + ((size_t)b * LL + l0) * N_SSM + n;
    const bf16* zp = xz + ((size_t)b * LL + l0) * N_XZ + DINNER + d;
    #pragma unroll 2
    for (int i = 0; i < LCH; ++i) {
        float dtv = *dtp;
        float uv  = (float)*up;
        float Bv  = (float)sp[0];
        float Cv  = (float)sp[DSTATE];
        float a   = __expf(dtv * A);
        h = fmaf(a, h, dtv * uv * Bv);
        float p = row16_sum(h * Cv);
        float zv = (float)*zp;
        float acc = fmaf(Dd, uv, p);
        acc *= zv / (1.f + __expf(-zv));
        if (n == 0) *up = __float2bfloat16(acc);
        dtp += DINNER; up += DINNER; sp += N_SSM; zp += N_XZ;
    }
}

extern "C" void kernel_launch(void* const* d_in, const int* in_sizes, int n_in,
                              void* d_out, int out_size, void* d_ws, size_t ws_size,
                              hipStream_t stream) {
    const float* x         = (const float*)d_in[0];
    const float* in_proj_w = (const float*)d_in[1];
    const float* conv_w    = (const float*)d_in[2];
    const float* conv_b    = (const float*)d_in[3];
    const float* x_proj_w  = (const float*)d_in[4];
    const float* dt_proj_w = (const float*)d_in[5];
    const float* dt_proj_b = (const float*)d_in[6];
    const float* A_log     = (const float*)d_in[7];
    const float* Dp        = (const float*)d_in[8];
    const float* out_proj_w= (const float*)d_in[9];
    float* out = (float*)d_out;

    // workspace layout (~80.4 MB); xbf aliases dt; chunkP/H alias Wt1/Wt2 (dead
    // after GEMMs 1 and 3, which complete before phase A launches).
    char* p = (char*)d_ws;
    float* dt   = (float*)p;                          p += (size_t)MM * DINNER * 4;
    bf16*  xbf  = (bf16*)dt;
    bf16*  xz   = (bf16*)p;                           p += (size_t)MM * N_XZ * 2;
    bf16*  u    = (bf16*)p;                           p += (size_t)MM * DINNER * 2;
    bf16*  ssm  = (bf16*)p;                           p += (size_t)MM * N_SSM * 2;
    bf16*  Wt1  = (bf16*)p;                           p += (size_t)N_XZ * DMODEL * 2;      // 8 MB
    bf16*  Wt2  = (bf16*)p;                           p += (size_t)N_SSM_PAD * DINNER * 2; // 8.9 MB
    bf16*  Wt3  = (bf16*)p;                           p += (size_t)DINNER * DINNER * 2;
    bf16*  Wt4  = (bf16*)p;                           p += (size_t)DMODEL * DINNER * 2;
    float* chunkP = (float*)Wt1;   // B*CCH*DINNER*16 f32 = 8 MB exactly
    float* chunkH = (float*)Wt2;   // 8 MB of Wt2's 8.9

    // 0) converts / transposes
    {
        int n = MM * DMODEL;
        cvt_kernel<<<(n + 255) / 256, 256, 0, stream>>>(x, xbf, n);
        transpose_cvt_kernel<<<dim3(N_XZ / 32, DMODEL / 32), 256, 0, stream>>>(in_proj_w, Wt1, DMODEL, N_XZ);
        transpose_cvt_kernel<<<dim3((N_SSM + 31) / 32, DINNER / 32), 256, 0, stream>>>(x_proj_w, Wt2, DINNER, N_SSM);
        transpose_cvt_kernel<<<dim3(DINNER / 32, DINNER / 32), 256, 0, stream>>>(dt_proj_w, Wt3, DINNER, DINNER);
        transpose_cvt_kernel<<<dim3(DMODEL / 32, DINNER / 32), 256, 0, stream>>>(out_proj_w, Wt4, DINNER, DMODEL);
    }
    // 1) xz = xbf @ W1   (2048 x 4096, K=1024), bf16
    mfma_gemm<0><<<dim3(N_XZ / TN, MM / TM), 256, 0, stream>>>(
        xbf, DMODEL, Wt1, DMODEL, nullptr, xz, N_XZ, nullptr, N_XZ, DMODEL);
    // 2) u = silu(conv(x_inner)+b)
    {
        int n = BB * LL * DINNER;
        conv_silu_kernel<<<(n + 255) / 256, 256, 0, stream>>>(xz, conv_w, conv_b, u);
    }
    // 3) ssm = u @ W2    (2048 x 2080, K=2048), bf16, col-guarded
    mfma_gemm<0><<<dim3(N_SSM_PAD / TN, MM / TM), 256, 0, stream>>>(
        u, DINNER, Wt2, DINNER, nullptr, ssm, N_SSM, nullptr, N_SSM, DINNER);
    // 4) dt = softplus(ssm[:,32:] @ W3 + b)  (2048 x 2048, K=2048), fp32
    mfma_gemm<1><<<dim3(DINNER / TN, MM / TM), 256, 0, stream>>>(
        ssm + 2 * DSTATE, N_SSM, Wt3, DINNER, dt, nullptr, DINNER, dt_proj_b, DINNER, DINNER);
    // 5) chunked selective scan: A (local), P (prefix), B (apply; y over u)
    scan_phase_a<<<dim3(DINNER / 16, CCH, BB), 256, 0, stream>>>(dt, u, ssm, A_log, chunkP, chunkH);
    scan_phase_p<<<dim3(BB * DINNER * DSTATE / 256), 256, 0, stream>>>(chunkP, chunkH);
    scan_phase_b<<<dim3(DINNER / 16, CCH, BB), 256, 0, stream>>>(dt, u, ssm, xz, A_log, Dp, chunkH);
    // 6) out = y @ W4    (2048 x 1024, K=2048), fp32
    mfma_gemm<2><<<dim3(DMODEL / TN, MM / TM), 256, 0, stream>>>(
        u, DINNER, Wt4, DINNER, out, nullptr, DMODEL, nullptr, DMODEL, DINNER);
}

// Round 7
// 421.270 us; speedup vs baseline: 5.8120x; 1.1788x over previous
//
#include <hip/hip_runtime.h>
#include <hip/hip_bf16.h>

// Dims (fixed for this problem)
#define BB 2
#define LL 1024
#define DMODEL 1024
#define DINNER 2048
#define DSTATE 16
#define DCONV 4
#define MM (BB * LL)          // 2048
#define N_XZ 4096
#define N_SSM 2080
#define N_SSM_PAD 2176        // 17 * 128
#define CCH 32                // chunks over L
#define LCH 32                // chunk length (CCH*LCH == LL)

typedef __hip_bfloat16 bf16;
typedef short bf16x8 __attribute__((ext_vector_type(8)));
typedef float f32x4 __attribute__((ext_vector_type(4)));

// ---------------- fp32 -> bf16 straight cast ----------------
__global__ void cvt_kernel(const float* __restrict__ in, bf16* __restrict__ out, int n) {
    int i = blockIdx.x * blockDim.x + threadIdx.x;
    if (i < n) out[i] = __float2bfloat16(in[i]);
}

// ---------------- transpose + cast: W fp32 [K,N] -> Wt bf16 [N,K] ----------------
__global__ void transpose_cvt_kernel(const float* __restrict__ in, bf16* __restrict__ out,
                                     int K, int N) {
    __shared__ float tile[32][33];
    const int nb = blockIdx.x * 32, kb = blockIdx.y * 32;
    const int tx = threadIdx.x & 31;
    const int ty = threadIdx.x >> 5;
    #pragma unroll
    for (int i = 0; i < 32; i += 8) {
        int k = kb + ty + i, n = nb + tx;
        tile[ty + i][tx] = (k < K && n < N) ? in[(size_t)k * N + n] : 0.f;
    }
    __syncthreads();
    #pragma unroll
    for (int i = 0; i < 32; i += 8) {
        int n = nb + ty + i, k = kb + tx;
        if (n < N && k < K) out[(size_t)n * K + k] = __float2bfloat16(tile[tx][ty + i]);
    }
}

// ---------------- MFMA GEMM: C[M,N] = A[M,K](bf16) @ Wt[N,K](bf16)^T ----------------
// EPI: 0 = bf16 store (col<N guard), 1 = +bias softplus f32, 2 = f32,
//      3 = cols<32 -> f32 BC sideband, cols in [32,N) -> bf16
#define TM 128
#define TN 128
#define TK 32
template<int EPI>
__global__ __launch_bounds__(256) void mfma_gemm(
    const bf16* __restrict__ A, int lda,
    const bf16* __restrict__ Wt, int ldw,
    float* __restrict__ Cf, bf16* __restrict__ Cb, int ldc,
    const float* __restrict__ bias,
    int N, int K)
{
    __shared__ __align__(16) bf16 As[TM][TK + 8];
    __shared__ __align__(16) bf16 Bs[TN][TK + 8];
    const int tid = threadIdx.x;
    const int wave = tid >> 6, lane = tid & 63;
    const int wm = (wave >> 1) * 64, wn = (wave & 1) * 64;
    const int m0 = blockIdx.y * TM, n0 = blockIdx.x * TN;
    const int lm = lane & 15;
    const int kq = lane >> 4;

    f32x4 acc[4][4] = {};

    const int sr = tid >> 2;
    const int sc = tid & 3;

    for (int k0 = 0; k0 < K; k0 += TK) {
        #pragma unroll
        for (int rd = 0; rd < 2; ++rd) {
            int row = rd * 64 + sr;
            uint4 v = *(const uint4*)(A + (size_t)(m0 + row) * lda + k0 + sc * 8);
            *(uint4*)(&As[row][sc * 8]) = v;
        }
        #pragma unroll
        for (int rd = 0; rd < 2; ++rd) {
            int row = rd * 64 + sr;
            uint4 v = *(const uint4*)(Wt + (size_t)(n0 + row) * ldw + k0 + sc * 8);
            *(uint4*)(&Bs[row][sc * 8]) = v;
        }
        __syncthreads();
        bf16x8 af[4], bfr[4];
        #pragma unroll
        for (int i = 0; i < 4; ++i)
            af[i] = *(const bf16x8*)(&As[wm + i * 16 + lm][kq * 8]);
        #pragma unroll
        for (int j = 0; j < 4; ++j)
            bfr[j] = *(const bf16x8*)(&Bs[wn + j * 16 + lm][kq * 8]);
        #pragma unroll
        for (int i = 0; i < 4; ++i)
            #pragma unroll
            for (int j = 0; j < 4; ++j)
                acc[i][j] = __builtin_amdgcn_mfma_f32_16x16x32_bf16(af[i], bfr[j], acc[i][j], 0, 0, 0);
        __syncthreads();
    }

    #pragma unroll
    for (int i = 0; i < 4; ++i) {
        #pragma unroll
        for (int j = 0; j < 4; ++j) {
            int gcol = n0 + wn + j * 16 + lm;
            if ((EPI == 0 || EPI == 3) && gcol >= N) continue;
            #pragma unroll
            for (int r = 0; r < 4; ++r) {
                int grow = m0 + wm + i * 16 + kq * 4 + r;
                float v = acc[i][j][r];
                if (EPI == 1) {
                    v += bias[gcol];
                    v = (v > 20.f) ? v : log1pf(__expf(v));
                    Cf[(size_t)grow * ldc + gcol] = v;
                } else if (EPI == 2) {
                    Cf[(size_t)grow * ldc + gcol] = v;
                } else if (EPI == 3) {
                    if (gcol < 32) Cf[(size_t)grow * 32 + gcol] = v;     // BC f32 sideband
                    else           Cb[(size_t)grow * ldc + gcol] = __float2bfloat16(v);
                } else {
                    Cb[(size_t)grow * ldc + gcol] = __float2bfloat16(v);
                }
            }
        }
    }
}

// ---------------- depthwise causal conv (k=4) + bias + SiLU (bf16 io) ----------------
__global__ void conv_silu_kernel(const bf16* __restrict__ xz,
                                 const float* __restrict__ conv_w,
                                 const float* __restrict__ conv_b,
                                 bf16* __restrict__ u)
{
    int idx = blockIdx.x * blockDim.x + threadIdx.x;
    if (idx >= BB * LL * DINNER) return;
    int d = idx & (DINNER - 1);
    int l = (idx >> 11) & (LL - 1);
    int b = idx >> 21;
    float acc = conv_b[d];
    #pragma unroll
    for (int j = 0; j < DCONV; ++j) {
        int ll = l - (DCONV - 1) + j;
        if (ll >= 0) {
            float xv = (float)xz[((size_t)(b * LL + ll)) * N_XZ + d];
            acc = fmaf(conv_w[d * DCONV + j], xv, acc);
        }
    }
    u[idx] = __float2bfloat16(acc / (1.f + __expf(-acc)));
}

// ---------------- scan phase A: lane per (b,d,chunk), h[16] in regs ----------------
// grid (DINNER/256, CCH, BB), block 256
__global__ __launch_bounds__(256) void scan_phase_a(
    const float* __restrict__ dt, const bf16* __restrict__ u,
    const float* __restrict__ BC,    // (B,L,32) f32: B=[0:16), C=[16:32)
    const float* __restrict__ A_log,
    float* __restrict__ chunkP, float* __restrict__ chunkH)
{
    const int d = blockIdx.x * 256 + threadIdx.x;
    const int c = blockIdx.y, b = blockIdx.z;
    const int l0 = c * LCH;

    float A[DSTATE];
    {
        const f32x4* ap = (const f32x4*)(A_log + d * DSTATE);
        #pragma unroll
        for (int q = 0; q < 4; ++q) {
            f32x4 v = ap[q];
            #pragma unroll
            for (int r = 0; r < 4; ++r) A[q * 4 + r] = -__expf(v[r]);
        }
    }
    float h[DSTATE];
    #pragma unroll
    for (int n = 0; n < DSTATE; ++n) h[n] = 0.f;
    float sdt = 0.f;

    const float* dtp = dt + ((size_t)b * LL + l0) * DINNER + d;
    const bf16* up = u + ((size_t)b * LL + l0) * DINNER + d;
    const float* bcp = BC + ((size_t)b * LL + l0) * 32;

    #pragma unroll 2
    for (int i = 0; i < LCH; ++i) {
        float dtv = *dtp;
        float uv  = (float)*up;
        float du  = dtv * uv;
        f32x4 Bv[4];
        #pragma unroll
        for (int q = 0; q < 4; ++q) Bv[q] = *(const f32x4*)(bcp + q * 4);
        #pragma unroll
        for (int n = 0; n < DSTATE; ++n) {
            float a = __expf(dtv * A[n]);
            h[n] = fmaf(a, h[n], du * Bv[n >> 2][n & 3]);
        }
        sdt += dtv;
        dtp += DINNER; up += DINNER; bcp += 32;
    }

    size_t idx = (((size_t)b * CCH + c) * DINNER + d) * DSTATE;
    #pragma unroll
    for (int q = 0; q < 4; ++q) {
        f32x4 pv, hv;
        #pragma unroll
        for (int r = 0; r < 4; ++r) { pv[r] = __expf(A[q * 4 + r] * sdt); hv[r] = h[q * 4 + r]; }
        *(f32x4*)(chunkP + idx + q * 4) = pv;
        *(f32x4*)(chunkH + idx + q * 4) = hv;
    }
}

// ---------------- scan phase P: exclusive prefix over chunks, in place on chunkH ----
__global__ __launch_bounds__(256) void scan_phase_p(
    const float* __restrict__ chunkP, float* __restrict__ chunkH)
{
    int gid = blockIdx.x * 256 + threadIdx.x;   // over B*DINNER*DSTATE = 65536
    int n = gid & 15;
    int d = (gid >> 4) & (DINNER - 1);
    int b = gid >> 15;
    const size_t stride = (size_t)DINNER * DSTATE;
    size_t idx = ((size_t)b * CCH * DINNER + d) * DSTATE + n;
    float H = 0.f;
    for (int c = 0; c < CCH; ++c) {
        float P  = chunkP[idx];
        float hl = chunkH[idx];
        chunkH[idx] = H;           // exclusive prefix
        H = fmaf(P, H, hl);
        idx += stride;
    }
}

// ---------------- scan phase B: lane per (b,d,chunk); gated y over u --------
__global__ __launch_bounds__(256) void scan_phase_b(
    const float* __restrict__ dt, bf16* __restrict__ u,
    const float* __restrict__ BC, const bf16* __restrict__ xz,
    const float* __restrict__ A_log, const float* __restrict__ Dp,
    const float* __restrict__ chunkH)
{
    const int d = blockIdx.x * 256 + threadIdx.x;
    const int c = blockIdx.y, b = blockIdx.z;
    const int l0 = c * LCH;

    float A[DSTATE];
    {
        const f32x4* ap = (const f32x4*)(A_log + d * DSTATE);
        #pragma unroll
        for (int q = 0; q < 4; ++q) {
            f32x4 v = ap[q];
            #pragma unroll
            for (int r = 0; r < 4; ++r) A[q * 4 + r] = -__expf(v[r]);
        }
    }
    const float Dd = Dp[d];
    float h[DSTATE];
    {
        size_t idx = (((size_t)b * CCH + c) * DINNER + d) * DSTATE;
        #pragma unroll
        for (int q = 0; q < 4; ++q) {
            f32x4 v = *(const f32x4*)(chunkH + idx + q * 4);
            #pragma unroll
            for (int r = 0; r < 4; ++r) h[q * 4 + r] = v[r];
        }
    }

    const float* dtp = dt + ((size_t)b * LL + l0) * DINNER + d;
    bf16* up = u + ((size_t)b * LL + l0) * DINNER + d;
    const float* bcp = BC + ((size_t)b * LL + l0) * 32;
    const bf16* zp = xz + ((size_t)b * LL + l0) * N_XZ + DINNER + d;

    #pragma unroll 2
    for (int i = 0; i < LCH; ++i) {
        float dtv = *dtp;
        float uv  = (float)*up;
        float du  = dtv * uv;
        f32x4 Bv[4], Cv[4];
        #pragma unroll
        for (int q = 0; q < 4; ++q) {
            Bv[q] = *(const f32x4*)(bcp + q * 4);
            Cv[q] = *(const f32x4*)(bcp + 16 + q * 4);
        }
        float acc = 0.f;
        #pragma unroll
        for (int n = 0; n < DSTATE; ++n) {
            float a = __expf(dtv * A[n]);
            h[n] = fmaf(a, h[n], du * Bv[n >> 2][n & 3]);
            acc = fmaf(h[n], Cv[n >> 2][n & 3], acc);
        }
        float zv = (float)*zp;
        acc = fmaf(Dd, uv, acc);
        acc *= zv / (1.f + __expf(-zv));
        *up = __float2bfloat16(acc);
        dtp += DINNER; up += DINNER; bcp += 32; zp += N_XZ;
    }
}

extern "C" void kernel_launch(void* const* d_in, const int* in_sizes, int n_in,
                              void* d_out, int out_size, void* d_ws, size_t ws_size,
                              hipStream_t stream) {
    const float* x         = (const float*)d_in[0];
    const float* in_proj_w = (const float*)d_in[1];
    const float* conv_w    = (const float*)d_in[2];
    const float* conv_b    = (const float*)d_in[3];
    const float* x_proj_w  = (const float*)d_in[4];
    const float* dt_proj_w = (const float*)d_in[5];
    const float* dt_proj_b = (const float*)d_in[6];
    const float* A_log     = (const float*)d_in[7];
    const float* Dp        = (const float*)d_in[8];
    const float* out_proj_w= (const float*)d_in[9];
    float* out = (float*)d_out;

    // workspace layout (~80.7 MB); xbf aliases dt; chunkP/H alias Wt1/Wt2 (dead
    // after GEMMs 1 and 3, which complete before phase A launches).
    char* p = (char*)d_ws;
    float* dt   = (float*)p;                          p += (size_t)MM * DINNER * 4;
    bf16*  xbf  = (bf16*)dt;
    bf16*  xz   = (bf16*)p;                           p += (size_t)MM * N_XZ * 2;
    bf16*  u    = (bf16*)p;                           p += (size_t)MM * DINNER * 2;
    bf16*  ssm  = (bf16*)p;                           p += (size_t)MM * N_SSM * 2;
    bf16*  Wt1  = (bf16*)p;                           p += (size_t)N_XZ * DMODEL * 2;      // 8 MB
    bf16*  Wt2  = (bf16*)p;                           p += (size_t)N_SSM_PAD * DINNER * 2; // 8.9 MB
    bf16*  Wt3  = (bf16*)p;                           p += (size_t)DINNER * DINNER * 2;
    bf16*  Wt4  = (bf16*)p;                           p += (size_t)DMODEL * DINNER * 2;
    float* BC   = (float*)p;                          p += (size_t)MM * 32 * 4;            // 256 KB
    float* chunkP = (float*)Wt1;   // B*CCH*DINNER*16 f32 = 8 MB exactly
    float* chunkH = (float*)Wt2;   // 8 MB of Wt2's 8.9

    // 0) converts / transposes
    {
        int n = MM * DMODEL;
        cvt_kernel<<<(n + 255) / 256, 256, 0, stream>>>(x, xbf, n);
        transpose_cvt_kernel<<<dim3(N_XZ / 32, DMODEL / 32), 256, 0, stream>>>(in_proj_w, Wt1, DMODEL, N_XZ);
        transpose_cvt_kernel<<<dim3((N_SSM + 31) / 32, DINNER / 32), 256, 0, stream>>>(x_proj_w, Wt2, DINNER, N_SSM);
        transpose_cvt_kernel<<<dim3(DINNER / 32, DINNER / 32), 256, 0, stream>>>(dt_proj_w, Wt3, DINNER, DINNER);
        transpose_cvt_kernel<<<dim3(DMODEL / 32, DINNER / 32), 256, 0, stream>>>(out_proj_w, Wt4, DINNER, DMODEL);
    }
    // 1) xz = xbf @ W1   (2048 x 4096, K=1024), bf16
    mfma_gemm<0><<<dim3(N_XZ / TN, MM / TM), 256, 0, stream>>>(
        xbf, DMODEL, Wt1, DMODEL, nullptr, xz, N_XZ, nullptr, N_XZ, DMODEL);
    // 2) u = silu(conv(x_inner)+b)
    {
        int n = BB * LL * DINNER;
        conv_silu_kernel<<<(n + 255) / 256, 256, 0, stream>>>(xz, conv_w, conv_b, u);
    }
    // 3) ssm = u @ W2    (2048 x 2080, K=2048); cols<32 -> BC f32, rest bf16
    mfma_gemm<3><<<dim3(N_SSM_PAD / TN, MM / TM), 256, 0, stream>>>(
        u, DINNER, Wt2, DINNER, BC, ssm, N_SSM, nullptr, N_SSM, DINNER);
    // 4) dt = softplus(ssm[:,32:] @ W3 + b)  (2048 x 2048, K=2048), fp32
    mfma_gemm<1><<<dim3(DINNER / TN, MM / TM), 256, 0, stream>>>(
        ssm + 2 * DSTATE, N_SSM, Wt3, DINNER, dt, nullptr, DINNER, dt_proj_b, DINNER, DINNER);
    // 5) chunked selective scan: A (local), P (prefix), B (apply; y over u)
    scan_phase_a<<<dim3(DINNER / 256, CCH, BB), 256, 0, stream>>>(dt, u, BC, A_log, chunkP, chunkH);
    scan_phase_p<<<dim3(BB * DINNER * DSTATE / 256), 256, 0, stream>>>(chunkP, chunkH);
    scan_phase_b<<<dim3(DINNER / 256, CCH, BB), 256, 0, stream>>>(dt, u, BC, xz, A_log, Dp, chunkH);
    // 6) out = y @ W4    (2048 x 1024, K=2048), fp32
    mfma_gemm<2><<<dim3(DMODEL / TN, MM / TM), 256, 0, stream>>>(
        u, DINNER, Wt4, DINNER, out, nullptr, DMODEL, nullptr, DMODEL, DINNER);
}

// Round 8
// 378.127 us; speedup vs baseline: 6.4751x; 1.1141x over previous
//
#include <hip/hip_runtime.h>
#include <hip/hip_bf16.h>

// Dims (fixed for this problem)
#define BB 2
#define LL 1024
#define DMODEL 1024
#define DINNER 2048
#define DSTATE 16
#define DCONV 4
#define MM (BB * LL)          // 2048
#define N_XZ 4096
#define N_SSM 2080
#define N_SSM_PAD 2176        // 34 * 64
#define CCH 32                // chunks over L
#define LCH 32                // chunk length (CCH*LCH == LL)

typedef __hip_bfloat16 bf16;
typedef short bf16x8 __attribute__((ext_vector_type(8)));
typedef float f32x4 __attribute__((ext_vector_type(4)));

// ---------------- async global -> LDS, 16B per lane ----------------
// HW scatters lane i to lds_base + i*16 (wave-uniform base, m104/m108).
__device__ __forceinline__ void load16_lds(const bf16* g, bf16* l) {
    __builtin_amdgcn_global_load_lds(
        (const __attribute__((address_space(1))) void*)g,
        (__attribute__((address_space(3))) void*)l,
        16, 0, 0);
}

// ---------------- fp32 -> bf16 straight cast ----------------
__global__ void cvt_kernel(const float* __restrict__ in, bf16* __restrict__ out, int n) {
    int i = blockIdx.x * blockDim.x + threadIdx.x;
    if (i < n) out[i] = __float2bfloat16(in[i]);
}

// ---------------- transpose + cast: W fp32 [K,N] -> Wt bf16 [N,K] ----------------
__global__ void transpose_cvt_kernel(const float* __restrict__ in, bf16* __restrict__ out,
                                     int K, int N) {
    __shared__ float tile[32][33];
    const int nb = blockIdx.x * 32, kb = blockIdx.y * 32;
    const int tx = threadIdx.x & 31;
    const int ty = threadIdx.x >> 5;
    #pragma unroll
    for (int i = 0; i < 32; i += 8) {
        int k = kb + ty + i, n = nb + tx;
        tile[ty + i][tx] = (k < K && n < N) ? in[(size_t)k * N + n] : 0.f;
    }
    __syncthreads();
    #pragma unroll
    for (int i = 0; i < 32; i += 8) {
        int n = nb + ty + i, k = kb + tx;
        if (n < N && k < K) out[(size_t)n * K + k] = __float2bfloat16(tile[tx][ty + i]);
    }
}

// ---------------- MFMA GEMM v2: 128x64 tile, global_load_lds staging --------------
// C[M,N] = A[M,K](bf16) @ Wt[N,K](bf16)^T
// EPI: 0 = bf16 store (col<N guard), 1 = +bias softplus f32, 2 = f32,
//      3 = cols<32 -> f32 BC sideband, cols in [32,N) -> bf16
#define TM 128
#define TN 64
#define TK 32
template<int EPI>
__global__ __launch_bounds__(256) void mfma_gemm(
    const bf16* __restrict__ A, int lda,
    const bf16* __restrict__ Wt, int ldw,
    float* __restrict__ Cf, bf16* __restrict__ Cb, int ldc,
    const float* __restrict__ bias,
    int N, int K)
{
    // unpadded: lane-contiguous order required by global_load_lds
    __shared__ __align__(16) bf16 As[TM * TK];   // [128][32]
    __shared__ __align__(16) bf16 Bs[TN * TK];   // [64][32]
    const int tid = threadIdx.x;
    const int wave = tid >> 6, lane = tid & 63;
    const int wm = (wave >> 1) * 64, wn = (wave & 1) * 32;
    const int m0 = blockIdx.y * TM, n0 = blockIdx.x * TN;
    const int lm = lane & 15;
    const int kq = lane >> 4;

    const int srow = lane >> 2;          // 0..15 within wave's 16-row slab
    const int scol = (lane & 3) * 8;     // element offset of 16B chunk

    f32x4 acc[4][2] = {};

    const bf16* Aw0 = A + (size_t)(m0 + wave * 16 + srow) * lda + scol;       // round 0
    const bf16* Aw1 = A + (size_t)(m0 + wave * 16 + 64 + srow) * lda + scol;  // round 1
    const bf16* Bw  = Wt + (size_t)(n0 + wave * 16 + srow) * ldw + scol;
    bf16* As0 = &As[(wave * 16) * TK];
    bf16* As1 = &As[(wave * 16 + 64) * TK];
    bf16* Bs0 = &Bs[(wave * 16) * TK];

    for (int k0 = 0; k0 < K; k0 += TK) {
        load16_lds(Aw0 + k0, As0);
        load16_lds(Aw1 + k0, As1);
        load16_lds(Bw + k0, Bs0);
        __syncthreads();   // drains vmcnt (global_load_lds) + lgkm

        bf16x8 af[4], bfr[2];
        #pragma unroll
        for (int i = 0; i < 4; ++i)
            af[i] = *(const bf16x8*)(&As[(wm + i * 16 + lm) * TK + kq * 8]);
        #pragma unroll
        for (int j = 0; j < 2; ++j)
            bfr[j] = *(const bf16x8*)(&Bs[(wn + j * 16 + lm) * TK + kq * 8]);
        #pragma unroll
        for (int i = 0; i < 4; ++i)
            #pragma unroll
            for (int j = 0; j < 2; ++j)
                acc[i][j] = __builtin_amdgcn_mfma_f32_16x16x32_bf16(af[i], bfr[j], acc[i][j], 0, 0, 0);
        __syncthreads();
    }

    // D layout: col = lane&15, row = (lane>>4)*4 + r (m89-verified)
    #pragma unroll
    for (int i = 0; i < 4; ++i) {
        #pragma unroll
        for (int j = 0; j < 2; ++j) {
            int gcol = n0 + wn + j * 16 + lm;
            if ((EPI == 0 || EPI == 3) && gcol >= N) continue;
            #pragma unroll
            for (int r = 0; r < 4; ++r) {
                int grow = m0 + wm + i * 16 + kq * 4 + r;
                float v = acc[i][j][r];
                if (EPI == 1) {
                    v += bias[gcol];
                    v = (v > 20.f) ? v : log1pf(__expf(v));
                    Cf[(size_t)grow * ldc + gcol] = v;
                } else if (EPI == 2) {
                    Cf[(size_t)grow * ldc + gcol] = v;
                } else if (EPI == 3) {
                    if (gcol < 32) Cf[(size_t)grow * 32 + gcol] = v;     // BC f32 sideband
                    else           Cb[(size_t)grow * ldc + gcol] = __float2bfloat16(v);
                } else {
                    Cb[(size_t)grow * ldc + gcol] = __float2bfloat16(v);
                }
            }
        }
    }
}

// ---------------- depthwise causal conv (k=4) + bias + SiLU (bf16 io) ----------------
__global__ void conv_silu_kernel(const bf16* __restrict__ xz,
                                 const float* __restrict__ conv_w,
                                 const float* __restrict__ conv_b,
                                 bf16* __restrict__ u)
{
    int idx = blockIdx.x * blockDim.x + threadIdx.x;
    if (idx >= BB * LL * DINNER) return;
    int d = idx & (DINNER - 1);
    int l = (idx >> 11) & (LL - 1);
    int b = idx >> 21;
    float acc = conv_b[d];
    #pragma unroll
    for (int j = 0; j < DCONV; ++j) {
        int ll = l - (DCONV - 1) + j;
        if (ll >= 0) {
            float xv = (float)xz[((size_t)(b * LL + ll)) * N_XZ + d];
            acc = fmaf(conv_w[d * DCONV + j], xv, acc);
        }
    }
    u[idx] = __float2bfloat16(acc / (1.f + __expf(-acc)));
}

// ---------------- scan phase A: lane per (b,d,chunk), h[16] in regs ----------------
__global__ __launch_bounds__(256) void scan_phase_a(
    const float* __restrict__ dt, const bf16* __restrict__ u,
    const float* __restrict__ BC,    // (B,L,32) f32: B=[0:16), C=[16:32)
    const float* __restrict__ A_log,
    float* __restrict__ chunkP, float* __restrict__ chunkH)
{
    const int d = blockIdx.x * 256 + threadIdx.x;
    const int c = blockIdx.y, b = blockIdx.z;
    const int l0 = c * LCH;

    float A[DSTATE];
    {
        const f32x4* ap = (const f32x4*)(A_log + d * DSTATE);
        #pragma unroll
        for (int q = 0; q < 4; ++q) {
            f32x4 v = ap[q];
            #pragma unroll
            for (int r = 0; r < 4; ++r) A[q * 4 + r] = -__expf(v[r]);
        }
    }
    float h[DSTATE];
    #pragma unroll
    for (int n = 0; n < DSTATE; ++n) h[n] = 0.f;
    float sdt = 0.f;

    const float* dtp = dt + ((size_t)b * LL + l0) * DINNER + d;
    const bf16* up = u + ((size_t)b * LL + l0) * DINNER + d;
    const float* bcp = BC + ((size_t)b * LL + l0) * 32;

    #pragma unroll 2
    for (int i = 0; i < LCH; ++i) {
        float dtv = *dtp;
        float uv  = (float)*up;
        float du  = dtv * uv;
        f32x4 Bv[4];
        #pragma unroll
        for (int q = 0; q < 4; ++q) Bv[q] = *(const f32x4*)(bcp + q * 4);
        #pragma unroll
        for (int n = 0; n < DSTATE; ++n) {
            float a = __expf(dtv * A[n]);
            h[n] = fmaf(a, h[n], du * Bv[n >> 2][n & 3]);
        }
        sdt += dtv;
        dtp += DINNER; up += DINNER; bcp += 32;
    }

    size_t idx = (((size_t)b * CCH + c) * DINNER + d) * DSTATE;
    #pragma unroll
    for (int q = 0; q < 4; ++q) {
        f32x4 pv, hv;
        #pragma unroll
        for (int r = 0; r < 4; ++r) { pv[r] = __expf(A[q * 4 + r] * sdt); hv[r] = h[q * 4 + r]; }
        *(f32x4*)(chunkP + idx + q * 4) = pv;
        *(f32x4*)(chunkH + idx + q * 4) = hv;
    }
}

// ---------------- scan phase P: exclusive prefix over chunks, in place on chunkH ----
__global__ __launch_bounds__(256) void scan_phase_p(
    const float* __restrict__ chunkP, float* __restrict__ chunkH)
{
    int gid = blockIdx.x * 256 + threadIdx.x;   // over B*DINNER*DSTATE = 65536
    int n = gid & 15;
    int d = (gid >> 4) & (DINNER - 1);
    int b = gid >> 15;
    const size_t stride = (size_t)DINNER * DSTATE;
    size_t idx = ((size_t)b * CCH * DINNER + d) * DSTATE + n;
    float H = 0.f;
    for (int c = 0; c < CCH; ++c) {
        float P  = chunkP[idx];
        float hl = chunkH[idx];
        chunkH[idx] = H;           // exclusive prefix
        H = fmaf(P, H, hl);
        idx += stride;
    }
}

// ---------------- scan phase B: lane per (b,d,chunk); gated y over u --------
__global__ __launch_bounds__(256) void scan_phase_b(
    const float* __restrict__ dt, bf16* __restrict__ u,
    const float* __restrict__ BC, const bf16* __restrict__ xz,
    const float* __restrict__ A_log, const float* __restrict__ Dp,
    const float* __restrict__ chunkH)
{
    const int d = blockIdx.x * 256 + threadIdx.x;
    const int c = blockIdx.y, b = blockIdx.z;
    const int l0 = c * LCH;

    float A[DSTATE];
    {
        const f32x4* ap = (const f32x4*)(A_log + d * DSTATE);
        #pragma unroll
        for (int q = 0; q < 4; ++q) {
            f32x4 v = ap[q];
            #pragma unroll
            for (int r = 0; r < 4; ++r) A[q * 4 + r] = -__expf(v[r]);
        }
    }
    const float Dd = Dp[d];
    float h[DSTATE];
    {
        size_t idx = (((size_t)b * CCH + c) * DINNER + d) * DSTATE;
        #pragma unroll
        for (int q = 0; q < 4; ++q) {
            f32x4 v = *(const f32x4*)(chunkH + idx + q * 4);
            #pragma unroll
            for (int r = 0; r < 4; ++r) h[q * 4 + r] = v[r];
        }
    }

    const float* dtp = dt + ((size_t)b * LL + l0) * DINNER + d;
    bf16* up = u + ((size_t)b * LL + l0) * DINNER + d;
    const float* bcp = BC + ((size_t)b * LL + l0) * 32;
    const bf16* zp = xz + ((size_t)b * LL + l0) * N_XZ + DINNER + d;

    #pragma unroll 2
    for (int i = 0; i < LCH; ++i) {
        float dtv = *dtp;
        float uv  = (float)*up;
        float du  = dtv * uv;
        f32x4 Bv[4], Cv[4];
        #pragma unroll
        for (int q = 0; q < 4; ++q) {
            Bv[q] = *(const f32x4*)(bcp + q * 4);
            Cv[q] = *(const f32x4*)(bcp + 16 + q * 4);
        }
        float acc = 0.f;
        #pragma unroll
        for (int n = 0; n < DSTATE; ++n) {
            float a = __expf(dtv * A[n]);
            h[n] = fmaf(a, h[n], du * Bv[n >> 2][n & 3]);
            acc = fmaf(h[n], Cv[n >> 2][n & 3], acc);
        }
        float zv = (float)*zp;
        acc = fmaf(Dd, uv, acc);
        acc *= zv / (1.f + __expf(-zv));
        *up = __float2bfloat16(acc);
        dtp += DINNER; up += DINNER; bcp += 32; zp += N_XZ;
    }
}

extern "C" void kernel_launch(void* const* d_in, const int* in_sizes, int n_in,
                              void* d_out, int out_size, void* d_ws, size_t ws_size,
                              hipStream_t stream) {
    const float* x         = (const float*)d_in[0];
    const float* in_proj_w = (const float*)d_in[1];
    const float* conv_w    = (const float*)d_in[2];
    const float* conv_b    = (const float*)d_in[3];
    const float* x_proj_w  = (const float*)d_in[4];
    const float* dt_proj_w = (const float*)d_in[5];
    const float* dt_proj_b = (const float*)d_in[6];
    const float* A_log     = (const float*)d_in[7];
    const float* Dp        = (const float*)d_in[8];
    const float* out_proj_w= (const float*)d_in[9];
    float* out = (float*)d_out;

    // workspace layout (~80.7 MB); xbf aliases dt; chunkP/H alias Wt1/Wt2
    char* p = (char*)d_ws;
    float* dt   = (float*)p;                          p += (size_t)MM * DINNER * 4;
    bf16*  xbf  = (bf16*)dt;
    bf16*  xz   = (bf16*)p;                           p += (size_t)MM * N_XZ * 2;
    bf16*  u    = (bf16*)p;                           p += (size_t)MM * DINNER * 2;
    bf16*  ssm  = (bf16*)p;                           p += (size_t)MM * N_SSM * 2;
    bf16*  Wt1  = (bf16*)p;                           p += (size_t)N_XZ * DMODEL * 2;      // 8 MB
    bf16*  Wt2  = (bf16*)p;                           p += (size_t)N_SSM_PAD * DINNER * 2; // 8.9 MB
    bf16*  Wt3  = (bf16*)p;                           p += (size_t)DINNER * DINNER * 2;
    bf16*  Wt4  = (bf16*)p;                           p += (size_t)DMODEL * DINNER * 2;
    float* BC   = (float*)p;                          p += (size_t)MM * 32 * 4;            // 256 KB
    float* chunkP = (float*)Wt1;   // B*CCH*DINNER*16 f32 = 8 MB exactly
    float* chunkH = (float*)Wt2;   // 8 MB of Wt2's 8.9

    // 0) converts / transposes
    {
        int n = MM * DMODEL;
        cvt_kernel<<<(n + 255) / 256, 256, 0, stream>>>(x, xbf, n);
        transpose_cvt_kernel<<<dim3(N_XZ / 32, DMODEL / 32), 256, 0, stream>>>(in_proj_w, Wt1, DMODEL, N_XZ);
        transpose_cvt_kernel<<<dim3((N_SSM + 31) / 32, DINNER / 32), 256, 0, stream>>>(x_proj_w, Wt2, DINNER, N_SSM);
        transpose_cvt_kernel<<<dim3(DINNER / 32, DINNER / 32), 256, 0, stream>>>(dt_proj_w, Wt3, DINNER, DINNER);
        transpose_cvt_kernel<<<dim3(DMODEL / 32, DINNER / 32), 256, 0, stream>>>(out_proj_w, Wt4, DINNER, DMODEL);
    }
    // 1) xz = xbf @ W1   (2048 x 4096, K=1024), bf16
    mfma_gemm<0><<<dim3(N_XZ / TN, MM / TM), 256, 0, stream>>>(
        xbf, DMODEL, Wt1, DMODEL, nullptr, xz, N_XZ, nullptr, N_XZ, DMODEL);
    // 2) u = silu(conv(x_inner)+b)
    {
        int n = BB * LL * DINNER;
        conv_silu_kernel<<<(n + 255) / 256, 256, 0, stream>>>(xz, conv_w, conv_b, u);
    }
    // 3) ssm = u @ W2    (2048 x 2080, K=2048); cols<32 -> BC f32, rest bf16
    mfma_gemm<3><<<dim3(N_SSM_PAD / TN, MM / TM), 256, 0, stream>>>(
        u, DINNER, Wt2, DINNER, BC, ssm, N_SSM, nullptr, N_SSM, DINNER);
    // 4) dt = softplus(ssm[:,32:] @ W3 + b)  (2048 x 2048, K=2048), fp32
    mfma_gemm<1><<<dim3(DINNER / TN, MM / TM), 256, 0, stream>>>(
        ssm + 2 * DSTATE, N_SSM, Wt3, DINNER, dt, nullptr, DINNER, dt_proj_b, DINNER, DINNER);
    // 5) chunked selective scan: A (local), P (prefix), B (apply; y over u)
    scan_phase_a<<<dim3(DINNER / 256, CCH, BB), 256, 0, stream>>>(dt, u, BC, A_log, chunkP, chunkH);
    scan_phase_p<<<dim3(BB * DINNER * DSTATE / 256), 256, 0, stream>>>(chunkP, chunkH);
    scan_phase_b<<<dim3(DINNER / 256, CCH, BB), 256, 0, stream>>>(dt, u, BC, xz, A_log, Dp, chunkH);
    // 6) out = y @ W4    (2048 x 1024, K=2048), fp32
    mfma_gemm<2><<<dim3(DMODEL / TN, MM / TM), 256, 0, stream>>>(
        u, DINNER, Wt4, DINNER, out, nullptr, DMODEL, nullptr, DMODEL, DINNER);
}